// Round 1
// baseline (384.479 us; speedup 1.0000x reference)
//
#include <hip/hip_runtime.h>
#include <hip/hip_bf16.h>
#include <math.h>

// Problem constants
#define N_TOK  16384
#define DMODEL 1024
#define GRAPHS 32
#define SEGLEN 512
#define HEADS  16
#define DH     64
#define D3     3072

typedef __bf16 bf16;
typedef __attribute__((ext_vector_type(4))) __bf16 bf16x4;
typedef __attribute__((ext_vector_type(8))) __bf16 bf16x8;
typedef __attribute__((ext_vector_type(4))) float f32x4;

// ---------------- fp32 -> bf16 convert (vectorized) ----------------
__global__ __launch_bounds__(256) void cvt_f32_bf16(const float* __restrict__ in,
                                                    bf16* __restrict__ out, int n4) {
    int i = blockIdx.x * blockDim.x + threadIdx.x;
    if (i < n4) {
        float4 v = ((const float4*)in)[i];
        bf16x4 o;
        o[0] = (bf16)v.x; o[1] = (bf16)v.y; o[2] = (bf16)v.z; o[3] = (bf16)v.w;
        ((bf16x4*)out)[i] = o;
    }
}

// ---------------- GEMM: C[M][N] = A[M][K] * B[N][K]^T (+bias, +resid) ----------------
// 128x128 tile, BK=64, 4 waves (2x2), 16x16x32 bf16 MFMA.
// LDS tiles stored as 16B chunks with XOR swizzle: chunk (row, kb) at row*8 + (kb ^ (row&7)).
template<int EPI>  // 0: store bf16 C + bias ; 1: store f32 C + bias + resid
__global__ __launch_bounds__(256) void gemm_bt(
    const bf16* __restrict__ A, const bf16* __restrict__ B,
    const float* __restrict__ bias, const float* __restrict__ resid,
    void* __restrict__ C, int M, int N, int K)
{
    __shared__ bf16x8 smA[128 * 8];
    __shared__ bf16x8 smB[128 * 8];
    const int bm0 = blockIdx.x * 128;
    const int bn0 = blockIdx.y * 128;
    const int tid = threadIdx.x;
    const int lane = tid & 63, w = tid >> 6;
    const int wr = w >> 1, wc = w & 1;
    const int l15 = lane & 15, l4 = lane >> 4;
    const int r7 = l15 & 7;

    f32x4 acc[4][4] = {};

    for (int k0 = 0; k0 < K; k0 += 64) {
        // stage A and B tiles: 1024 chunks each of 16B; 256 threads x 4
        #pragma unroll
        for (int q = 0; q < 4; q++) {
            int c = tid + 256 * q;
            int row = c >> 3, kb = c & 7;
            uint4 ga = *(const uint4*)((const char*)A + (size_t)(bm0 + row) * K * 2 + (size_t)k0 * 2 + kb * 16);
            smA[row * 8 + (kb ^ (row & 7))] = __builtin_bit_cast(bf16x8, ga);
            uint4 gb = *(const uint4*)((const char*)B + (size_t)(bn0 + row) * K * 2 + (size_t)k0 * 2 + kb * 16);
            smB[row * 8 + (kb ^ (row & 7))] = __builtin_bit_cast(bf16x8, gb);
        }
        __syncthreads();
        #pragma unroll
        for (int kp = 0; kp < 2; kp++) {
            int slot = kp * 4 + l4;
            bf16x8 af[4], bfr[4];
            #pragma unroll
            for (int m = 0; m < 4; m++)
                af[m] = smA[(wr * 64 + m * 16 + l15) * 8 + (slot ^ r7)];
            #pragma unroll
            for (int n = 0; n < 4; n++)
                bfr[n] = smB[(wc * 64 + n * 16 + l15) * 8 + (slot ^ r7)];
            #pragma unroll
            for (int m = 0; m < 4; m++)
                #pragma unroll
                for (int n = 0; n < 4; n++)
                    acc[m][n] = __builtin_amdgcn_mfma_f32_16x16x32_bf16(af[m], bfr[n], acc[m][n], 0, 0, 0);
        }
        __syncthreads();
    }

    // epilogue: C/D layout col=lane&15, row=(lane>>4)*4+i
    #pragma unroll
    for (int m = 0; m < 4; m++) {
        #pragma unroll
        for (int n = 0; n < 4; n++) {
            int col = bn0 + wc * 64 + n * 16 + l15;
            float bv = bias[col];
            #pragma unroll
            for (int i = 0; i < 4; i++) {
                int row = bm0 + wr * 64 + m * 16 + l4 * 4 + i;
                float v = acc[m][n][i] + bv;
                if (EPI == 0) {
                    ((bf16*)C)[(size_t)row * N + col] = (bf16)v;
                } else {
                    v += resid[(size_t)row * N + col];
                    ((float*)C)[(size_t)row * N + col] = v;
                }
            }
        }
    }
}

// ---------------- block-diagonal flash attention ----------------
// grid: (qt=8, h=16, g=32); block = 256 threads (4 waves), each wave owns 16 q-rows.
// Q/K tiles [64 rows][64 cols] bf16 swizzled; V stored transposed (row = dh col).
__global__ __launch_bounds__(256) void attn_kernel(
    const bf16* __restrict__ qkv, bf16* __restrict__ ctx)
{
    const int qt = blockIdx.x, h = blockIdx.y, g = blockIdx.z;
    __shared__ bf16x8 smQ[64 * 8];
    __shared__ bf16x8 smK[64 * 8];
    __shared__ bf16x8 smV[64 * 8];   // transposed: [dh col][kv]
    __shared__ bf16x8 smP[64 * 8];
    const int tid = threadIdx.x, lane = tid & 63, w = tid >> 6;
    const int l15 = lane & 15, l4 = lane >> 4;
    const int grow0 = g * SEGLEN;

    // load Q tile: rows grow0 + qt*64 + r, cols h*64..+64
    #pragma unroll
    for (int q = 0; q < 2; q++) {
        int c = tid + 256 * q;
        int row = c >> 3, kb = c & 7;
        uint4 v = *(const uint4*)(qkv + (size_t)(grow0 + qt * 64 + row) * D3 + h * 64 + kb * 8);
        smQ[row * 8 + (kb ^ (row & 7))] = __builtin_bit_cast(bf16x8, v);
    }
    __syncthreads();

    // hoist Q fragments (warp's 16 rows)
    bf16x8 qf[2];
    #pragma unroll
    for (int kp = 0; kp < 2; kp++) {
        int row = w * 16 + l15;
        qf[kp] = smQ[row * 8 + ((kp * 4 + l4) ^ (row & 7))];
    }

    f32x4 acc[4] = {};
    float mrow[4], lrow[4];
    #pragma unroll
    for (int i = 0; i < 4; i++) { mrow[i] = -INFINITY; lrow[i] = 0.f; }
    const float scale = 0.125f;  // 1/sqrt(64)

    for (int t = 0; t < 8; ++t) {
        // stage K tile
        #pragma unroll
        for (int q = 0; q < 2; q++) {
            int c = tid + 256 * q;
            int row = c >> 3, kb = c & 7;
            uint4 v = *(const uint4*)(qkv + (size_t)(grow0 + t * 64 + row) * D3 + 1024 + h * 64 + kb * 8);
            smK[row * 8 + (kb ^ (row & 7))] = __builtin_bit_cast(bf16x8, v);
        }
        // stage V transposed: Vt[cd][kv], bf16 idx = cd*64 + (kv ^ ((cd&7)<<3))
        #pragma unroll
        for (int q = 0; q < 2; q++) {
            int c = tid + 256 * q;
            int kv = c >> 3, kb = c & 7;
            uint4 v = *(const uint4*)(qkv + (size_t)(grow0 + t * 64 + kv) * D3 + 2048 + h * 64 + kb * 8);
            bf16x8 b = __builtin_bit_cast(bf16x8, v);
            #pragma unroll
            for (int j = 0; j < 8; j++) {
                int cd = kb * 8 + j;
                ((bf16*)smV)[cd * 64 + (kv ^ ((cd & 7) << 3))] = b[j];
            }
        }
        __syncthreads();

        // S = Q K^T (16 q-rows x 64 kv)
        f32x4 s[4] = {};
        #pragma unroll
        for (int kp = 0; kp < 2; kp++) {
            #pragma unroll
            for (int n = 0; n < 4; n++) {
                int row = n * 16 + l15;
                bf16x8 kf = smK[row * 8 + ((kp * 4 + l4) ^ (row & 7))];
                s[n] = __builtin_amdgcn_mfma_f32_16x16x32_bf16(qf[kp], kf, s[n], 0, 0, 0);
            }
        }
        // scale + row max (across 4 frags then across 16 lanes)
        float mnew[4];
        #pragma unroll
        for (int i = 0; i < 4; i++) {
            #pragma unroll
            for (int n = 0; n < 4; n++) s[n][i] *= scale;
            float mx = fmaxf(fmaxf(s[0][i], s[1][i]), fmaxf(s[2][i], s[3][i]));
            #pragma unroll
            for (int d = 1; d < 16; d <<= 1) mx = fmaxf(mx, __shfl_xor(mx, d));
            mnew[i] = fmaxf(mrow[i], mx);
        }
        // P = exp(s - mnew) -> LDS (bf16, swizzled), rowsum
        float rsum[4] = {0.f, 0.f, 0.f, 0.f};
        #pragma unroll
        for (int n = 0; n < 4; n++) {
            #pragma unroll
            for (int i = 0; i < 4; i++) {
                float p = __expf(s[n][i] - mnew[i]);
                rsum[i] += p;
                int prow = w * 16 + l4 * 4 + i;
                int pcol = n * 16 + l15;
                ((bf16*)smP)[prow * 64 + (pcol ^ ((prow & 7) << 3))] = (bf16)p;
            }
        }
        #pragma unroll
        for (int i = 0; i < 4; i++) {
            #pragma unroll
            for (int d = 1; d < 16; d <<= 1) rsum[i] += __shfl_xor(rsum[i], d);
            float alpha = __expf(mrow[i] - mnew[i]);   // first tile: exp(-inf)=0
            lrow[i] = lrow[i] * alpha + rsum[i];
            mrow[i] = mnew[i];
            #pragma unroll
            for (int n = 0; n < 4; n++) acc[n][i] *= alpha;
        }
        // PV: acc += P * V   (P rows = warp's own 16 rows -> no cross-warp hazard)
        #pragma unroll
        for (int kp = 0; kp < 2; kp++) {
            int prow = w * 16 + l15;
            bf16x8 pf = smP[prow * 8 + ((kp * 4 + l4) ^ (prow & 7))];
            #pragma unroll
            for (int n = 0; n < 4; n++) {
                int vrow = n * 16 + l15;
                bf16x8 vf = smV[vrow * 8 + ((kp * 4 + l4) ^ (vrow & 7))];
                acc[n] = __builtin_amdgcn_mfma_f32_16x16x32_bf16(pf, vf, acc[n], 0, 0, 0);
            }
        }
        __syncthreads();
    }

    // epilogue: ctx[row][h*64 + col] = acc / l
    #pragma unroll
    for (int i = 0; i < 4; i++) {
        float inv = 1.f / lrow[i];
        int row = grow0 + qt * 64 + w * 16 + l4 * 4 + i;
        #pragma unroll
        for (int n = 0; n < 4; n++) {
            int col = h * 64 + n * 16 + l15;
            ctx[(size_t)row * DMODEL + col] = (bf16)(acc[n][i] * inv);
        }
    }
}

// ---------------- residual+GEMM output -> LayerNorm ----------------
__global__ __launch_bounds__(256) void ln_kernel(
    const float* __restrict__ h, const float* __restrict__ gamma,
    const float* __restrict__ beta, float* __restrict__ out)
{
    const int row = blockIdx.x;
    float4 v = ((const float4*)(h + (size_t)row * DMODEL))[threadIdx.x];
    float s  = v.x + v.y + v.z + v.w;
    float ss = v.x * v.x + v.y * v.y + v.z * v.z + v.w * v.w;
    #pragma unroll
    for (int d = 1; d < 64; d <<= 1) { s += __shfl_xor(s, d); ss += __shfl_xor(ss, d); }
    __shared__ float red[8];
    int wv = threadIdx.x >> 6, lane = threadIdx.x & 63;
    if (lane == 0) { red[wv] = s; red[4 + wv] = ss; }
    __syncthreads();
    s  = red[0] + red[1] + red[2] + red[3];
    ss = red[4] + red[5] + red[6] + red[7];
    float mu  = s * (1.f / 1024.f);
    float var = ss * (1.f / 1024.f) - mu * mu;
    float rs  = rsqrtf(var + 1e-5f);
    float4 gv = ((const float4*)gamma)[threadIdx.x];
    float4 bv = ((const float4*)beta)[threadIdx.x];
    float4 o;
    o.x = (v.x - mu) * rs * gv.x + bv.x;
    o.y = (v.y - mu) * rs * gv.y + bv.y;
    o.z = (v.z - mu) * rs * gv.z + bv.z;
    o.w = (v.w - mu) * rs * gv.w + bv.w;
    ((float4*)(out + (size_t)row * DMODEL))[threadIdx.x] = o;
}

// ---------------- launch ----------------
extern "C" void kernel_launch(void* const* d_in, const int* in_sizes, int n_in,
                              void* d_out, int out_size, void* d_ws, size_t ws_size,
                              hipStream_t stream) {
    const float* x     = (const float*)d_in[0];
    // d_in[1] = batch (int64) — segments are fixed (512 each), unused
    const float* w_in  = (const float*)d_in[2];
    const float* b_in  = (const float*)d_in[3];
    const float* w_out = (const float*)d_in[4];
    const float* b_out = (const float*)d_in[5];
    const float* gamma = (const float*)d_in[6];
    const float* beta  = (const float*)d_in[7];
    float* out = (float*)d_out;

    // workspace layout (all offsets 256B aligned), ~136 MB total:
    //   [0, 32M)        xb  (bf16 x)        -> later reused as ctx (bf16)
    //   [32M, 38M)      wb  (bf16 w_in)
    //   [38M, 40M)      wob (bf16 w_out)
    //   [40M, 136M)     qkv (bf16, N x 3072) -> later reused as h (f32, N x 1024)
    char* ws = (char*)d_ws;
    bf16*  xb   = (bf16*)ws;
    bf16*  wb   = (bf16*)(ws + 33554432);
    bf16*  wob  = (bf16*)(ws + 33554432 + 6291456);
    bf16*  qkv  = (bf16*)(ws + 33554432 + 6291456 + 2097152);
    bf16*  ctxb = xb;            // alias: xb dead after GEMM1
    float* hbuf = (float*)qkv;   // alias: qkv dead after attention

    // 1) converts
    cvt_f32_bf16<<<16384, 256, 0, stream>>>(x,     xb,  N_TOK * DMODEL / 4);
    cvt_f32_bf16<<<3072,  256, 0, stream>>>(w_in,  wb,  D3 * DMODEL / 4);
    cvt_f32_bf16<<<1024,  256, 0, stream>>>(w_out, wob, DMODEL * DMODEL / 4);

    // 2) qkv = x @ w_in.T + b_in  (bf16 out)
    gemm_bt<0><<<dim3(128, 24), 256, 0, stream>>>(xb, wb, b_in, nullptr, qkv,
                                                  N_TOK, D3, DMODEL);
    // 3) block-diagonal attention -> ctx (bf16)
    attn_kernel<<<dim3(8, 16, 32), 256, 0, stream>>>(qkv, ctxb);

    // 4) h = ctx @ w_out.T + b_out + x  (f32 out)
    gemm_bt<1><<<dim3(128, 8), 256, 0, stream>>>(ctxb, wob, b_out, x, hbuf,
                                                 N_TOK, DMODEL, DMODEL);
    // 5) LayerNorm
    ln_kernel<<<N_TOK, 256, 0, stream>>>(hbuf, gamma, beta, out);
}